// Round 14
// baseline (597.533 us; speedup 1.0000x reference)
//
#include <hip/hip_runtime.h>

// WaveCell v14: v13 + LDS double-buffering (one barrier per shot).
// B=4, NZ=NX=2048, fp32, periodic wrap (pow2 dims).
//
// v13 (harness 591us, est dispatch ~181us): CU-side traffic 0.78GB at
// ~4.9 TB/s — BELOW the ~6.3 TB/s CU-side cap v4 demonstrated. Residual
// ~35us over the ~145us floor = per-shot barrier structure (2 syncs,
// stage and compute strictly serialized).
// v14: two 28KB LDS buffers. Iter b: ds_write shot b+1 -> buf[(b+1)&1]
// WHILE computing shot b from buf[b&1]; one barrier at end of iter.
// Hazards: writes hit the opposite buffer (safe within iter); reuse of a
// buffer is 2 iterations = 2 barriers away (safe). sv regs reused (zero
// extra VGPR). Cost: 56KB LDS -> 2 blocks/CU (v11: wave count has weak
// effect; accepted risk). Pre-commit: flat/regress -> v13 is the plateau.

constexpr int NZ = 2048;
constexpr int NX = 2048;
constexpr int B  = 4;
constexpr int PLANE = NZ * NX;      // 4,194,304
constexpr int VOL   = B * PLANE;    // 16,777,216
constexpr float DT    = 1e-3f;
constexpr float INV_H = 0.1f;       // 1/10m

constexpr int ZB   = 8;             // z-rows per block
constexpr int XR   = 128;           // x-points per block
constexpr int NROW = ZB + 2;        // staged rows z0-1 .. z0+8
constexpr int RF4  = 34;            // float4 per staged row (x0-4 .. x0+131)
constexpr int ROWF = 140;           // LDS row stride (floats), 136 + 4 pad
constexpr int F4PF = NROW * RF4;    // 340 float4 per field
constexpr int TOT  = 5 * F4PF;      // 1700 float4 staged per shot
constexpr int BUF  = 5 * NROW * ROWF;      // 7000 floats per buffer
constexpr int NBLK = PLANE / (ZB * XR);    // 4096
constexpr int NXCD = 8;
constexpr int BLK_PER_XCD = NBLK / NXCD;   // 512

typedef float f32x4 __attribute__((ext_vector_type(4)));

__device__ __forceinline__ float rcpf(float x) { return __builtin_amdgcn_rcpf(x); }
__device__ __forceinline__ float4 ld4(const float* __restrict__ p) {
    return *reinterpret_cast<const float4*>(p);
}
__device__ __forceinline__ void st4(float* __restrict__ p,
                                    float a, float b, float c, float d) {
    f32x4 v = {a, b, c, d};
    *reinterpret_cast<f32x4*>(p) = v;   // plain cached store (v9-proven)
}

__global__ __launch_bounds__(256) void wave_fused_v14(
    const float* __restrict__ vp,  const float* __restrict__ vs,
    const float* __restrict__ rho,
    const float* __restrict__ vx,  const float* __restrict__ vz,
    const float* __restrict__ txx, const float* __restrict__ tzz,
    const float* __restrict__ txz,
    const float* __restrict__ dd,
    float* __restrict__ out)
{
    __shared__ float lds[2 * BUF];   // 56,000 B

    // XCD-band swizzle: XCD k owns 512 consecutive sb = 32 z-tiles = 256
    // contiguous z-rows -> halo rows L2-local.
    const int bid = blockIdx.x;
    const int sb  = (bid & (NXCD - 1)) * BLK_PER_XCD + (bid >> 3);
    const int tz  = sb >> 4;                 // 256 z-tiles
    const int tx  = sb & 15;                 // 16 x-tiles
    const int z0  = tz << 3;
    const int x0  = tx << 7;
    const int tid = threadIdx.x;
    const int xt  = tid & 31;                // 32 x-threads (4 pts each)
    const int zt  = tid >> 5;                // 8 z-threads

    const int z   = z0 + zt;
    const int x   = x0 + (xt << 2);
    const int zp  = (z + 1) & (NZ - 1);
    const int zm  = (z - 1) & (NZ - 1);
    const int xm1 = (x - 1) & (NX - 1);
    const int xp4 = (x + 4) & (NX - 1);
    const int rz  = z  * NX;
    const int rzp = zp * NX;
    const int rzm = zm * NX;

    // ---------- hoisted staging addresses (b-invariant) ----------
    const float* sp[7];
    int dst7[7];
    {
        #pragma unroll
        for (int k = 0; k < 7; ++k) {
            const int idx = k * 256 + tid;
            const int f   = idx / F4PF;              // 0..4 (5 when inactive)
            const int rem = idx - f * F4PF;
            const int rr  = rem / RF4;
            const int c   = rem - rr * RF4;
            const int gz  = (z0 - 1 + rr) & (NZ - 1);
            const int gx  = (x0 - 4 + (c << 2)) & (NX - 1);
            const float* fp = (f == 0) ? txx : (f == 1) ? txz
                            : (f == 2) ? tzz : (f == 3) ? vx
                            : (f == 4) ? vz  : txx;   // f==5: inactive lanes
            sp[k]   = fp + gz * NX + gx;
            dst7[k] = (f * NROW + rr) * ROWF + (c << 2);
        }
    }
    const bool act6 = tid < (TOT - 6 * 256);         // tid < 164

    // ---------- per-thread coefficients (regs, amortized over shots) -------
    float dz6[6], rz6[6];
    {
        const float4 d4 = ld4(dd + rz + x);
        dz6[0] = dd[rz + xm1]; dz6[1] = d4.x; dz6[2] = d4.y;
        dz6[3] = d4.z;         dz6[4] = d4.w; dz6[5] = dd[rz + xp4];
        const float4 r4 = ld4(rho + rz + x);
        rz6[0] = rho[rz + xm1]; rz6[1] = r4.x; rz6[2] = r4.y;
        rz6[3] = r4.z;          rz6[4] = r4.w; rz6[5] = rho[rz + xp4];
    }
    float avz[6], bvz[6], inv_c[4];
    #pragma unroll
    for (int j = 0; j < 6; ++j) {
        const float c   = 0.5f * DT * dz6[j];
        const float inv = rcpf(1.0f + c);
        avz[j] = (1.0f - c) * inv;
        bvz[j] = DT * INV_H * inv * rcpf(rz6[j]);
        if (j >= 1 && j <= 4) inv_c[j - 1] = inv;
    }
    float avzp[4], bvzp[4], avzm[4], bvzm[4];
    {
        const float4 dp = ld4(dd + rzp + x), dm = ld4(dd + rzm + x);
        const float4 rp = ld4(rho + rzp + x), rm = ld4(rho + rzm + x);
        const float dpa[4] = {dp.x, dp.y, dp.z, dp.w};
        const float dma[4] = {dm.x, dm.y, dm.z, dm.w};
        const float rpa[4] = {rp.x, rp.y, rp.z, rp.w};
        const float rma[4] = {rm.x, rm.y, rm.z, rm.w};
        #pragma unroll
        for (int k = 0; k < 4; ++k) {
            float c = 0.5f * DT * dpa[k];
            float inv = rcpf(1.0f + c);
            avzp[k] = (1.0f - c) * inv;
            bvzp[k] = DT * INV_H * inv * rcpf(rpa[k]);
            c = 0.5f * DT * dma[k];
            inv = rcpf(1.0f + c);
            avzm[k] = (1.0f - c) * inv;
            bvzm[k] = DT * INV_H * inv * rcpf(rma[k]);
        }
    }
    float q1[4], q2[4], q3[4];
    {
        const float4 vp4 = ld4(vp + rz + x), vs4 = ld4(vs + rz + x);
        const float vpa[4] = {vp4.x, vp4.y, vp4.z, vp4.w};
        const float vsa[4] = {vs4.x, vs4.y, vs4.z, vs4.w};
        #pragma unroll
        for (int k = 0; k < 4; ++k) {
            const float r   = rz6[k + 1];
            const float muv = r * vsa[k] * vsa[k];
            const float lam = r * vpa[k] * vpa[k] - 2.0f * muv;
            const float bsH = DT * INV_H * inv_c[k];
            q1[k] = bsH * (lam + 2.0f * muv);
            q2[k] = bsH * lam;
            q3[k] = bsH * muv;
        }
    }

    // LDS compute bases (within a buffer): staged row 0 = global z0-1.
    const int lx   = 4 + (xt << 2);
    const int rowT = (0 * NROW + zt) * ROWF + lx;   // +ROWF = row z
    const int rowX = (1 * NROW + zt) * ROWF + lx;
    const int rowZ = (2 * NROW + zt) * ROWF + lx;
    const int rowV = (3 * NROW + zt) * ROWF + lx;
    const int rowW = (4 * NROW + zt) * ROWF + lx;
    auto L4 = [&](int off) -> f32x4 {
        return *reinterpret_cast<const f32x4*>(&lds[off]);
    };

    // ---------- prologue: shot 0 -> buf0; shot 1 -> sv ----------
    f32x4 sv[7];
    #pragma unroll
    for (int k = 0; k < 7; ++k)
        sv[k] = *reinterpret_cast<const f32x4*>(sp[k]);
    #pragma unroll
    for (int k = 0; k < 6; ++k)
        *reinterpret_cast<f32x4*>(&lds[dst7[k]]) = sv[k];
    if (act6)
        *reinterpret_cast<f32x4*>(&lds[dst7[6]]) = sv[6];
    #pragma unroll
    for (int k = 0; k < 7; ++k)
        sv[k] = *reinterpret_cast<const f32x4*>(sp[k] + PLANE);
    __syncthreads();

    // ---------- main loop: one barrier per shot ----------
    #pragma unroll 1
    for (int b = 0; b < B; ++b) {
        const int cbase = (b & 1) * BUF;

        if (b < B - 1) {                 // write shot b+1 into other buffer
            const int woff = ((b + 1) & 1) * BUF;
            #pragma unroll
            for (int k = 0; k < 6; ++k)
                *reinterpret_cast<f32x4*>(&lds[woff + dst7[k]]) = sv[k];
            if (act6)
                *reinterpret_cast<f32x4*>(&lds[woff + dst7[6]]) = sv[6];
        }
        if (b < B - 2) {                 // prefetch shot b+2 into dead regs
            const int nb3 = (b + 2) * PLANE;
            #pragma unroll
            for (int k = 0; k < 7; ++k)
                sv[k] = *reinterpret_cast<const f32x4*>(sp[k] + nb3);
        }

        // ---- gather row segments from LDS (all aligned ds_read_b128) ----
        float txxz[6], txzz[6], tzzz[5], tzzzp[5], txxzp[5];
        float txzzm[5], vxz[5], vzz[5];
        float txzzp4[4], tzzzm4[4], vxzp4[4], vzzm4[4];
        {
            f32x4 m, e;
            m = L4(cbase + rowT + ROWF);      e = L4(cbase + rowT + ROWF - 4);
            txxz[1] = m.x; txxz[2] = m.y; txxz[3] = m.z; txxz[4] = m.w;
            txxz[0] = e.w;            e = L4(cbase + rowT + ROWF + 4);
            txxz[5] = e.x;
            m = L4(cbase + rowX + ROWF);      e = L4(cbase + rowX + ROWF - 4);
            txzz[1] = m.x; txzz[2] = m.y; txzz[3] = m.z; txzz[4] = m.w;
            txzz[0] = e.w;            e = L4(cbase + rowX + ROWF + 4);
            txzz[5] = e.x;
            m = L4(cbase + rowZ + ROWF);      e = L4(cbase + rowZ + ROWF - 4);
            tzzz[1] = m.x; tzzz[2] = m.y; tzzz[3] = m.z; tzzz[4] = m.w;
            tzzz[0] = e.w;
            m = L4(cbase + rowZ + 2 * ROWF);  e = L4(cbase + rowZ + 2 * ROWF - 4);
            tzzzp[1] = m.x; tzzzp[2] = m.y; tzzzp[3] = m.z; tzzzp[4] = m.w;
            tzzzp[0] = e.w;
            m = L4(cbase + rowT + 2 * ROWF);  e = L4(cbase + rowT + 2 * ROWF - 4);
            txxzp[1] = m.x; txxzp[2] = m.y; txxzp[3] = m.z; txxzp[4] = m.w;
            txxzp[0] = e.w;
            m = L4(cbase + rowX);             e = L4(cbase + rowX + 4);
            txzzm[0] = m.x; txzzm[1] = m.y; txzzm[2] = m.z; txzzm[3] = m.w;
            txzzm[4] = e.x;
            m = L4(cbase + rowV + ROWF);      e = L4(cbase + rowV + ROWF + 4);
            vxz[0] = m.x; vxz[1] = m.y; vxz[2] = m.z; vxz[3] = m.w;
            vxz[4] = e.x;
            m = L4(cbase + rowW + ROWF);      e = L4(cbase + rowW + ROWF - 4);
            vzz[1] = m.x; vzz[2] = m.y; vzz[3] = m.z; vzz[4] = m.w;
            vzz[0] = e.w;
            m = L4(cbase + rowX + 2 * ROWF);
            txzzp4[0] = m.x; txzzp4[1] = m.y; txzzp4[2] = m.z; txzzp4[3] = m.w;
            m = L4(cbase + rowZ);
            tzzzm4[0] = m.x; tzzzm4[1] = m.y; tzzzm4[2] = m.z; tzzzm4[3] = m.w;
            m = L4(cbase + rowV + 2 * ROWF);
            vxzp4[0] = m.x; vxzp4[1] = m.y; vxzp4[2] = m.z; vxzp4[3] = m.w;
            m = L4(cbase + rowW);
            vzzm4[0] = m.x; vzzm4[1] = m.y; vzzm4[2] = m.z; vzzm4[3] = m.w;
        }

        // --- new velocities (leapfrog: from old stresses) ---
        float vxn_z[5];
        #pragma unroll
        for (int k = 0; k < 5; ++k)
            vxn_z[k] = avz[k + 1] * vxz[k]
                     + bvz[k + 1] * ((txxz[k + 1] - txxz[k])
                                   + (txzz[k + 1] - txzzm[k]));
        float vzn_z[5];
        #pragma unroll
        for (int k = 0; k < 5; ++k)
            vzn_z[k] = avz[k] * vzz[k]
                     + bvz[k] * ((txzz[k + 1] - txzz[k])
                               + (tzzzp[k] - tzzz[k]));
        float vxn_zp[4];
        #pragma unroll
        for (int k = 0; k < 4; ++k)
            vxn_zp[k] = avzp[k] * vxzp4[k]
                      + bvzp[k] * ((txxzp[k + 1] - txxzp[k])
                                 + (txzzp4[k] - txzz[k + 1]));
        float vzn_zm[4];
        #pragma unroll
        for (int k = 0; k < 4; ++k)
            vzn_zm[k] = avzm[k] * vzzm4[k]
                      + bvzm[k] * ((txzzm[k + 1] - txzzm[k])
                                 + (tzzz[k + 1] - tzzzm4[k]));

        // --- stress update (from new velocities) ---
        float oxx[4], ozz[4], oxz[4];
        #pragma unroll
        for (int k = 0; k < 4; ++k) {
            const float dvx = vxn_z[k + 1] - vxn_z[k];
            const float dvz = vzn_z[k + 1] - vzn_zm[k];
            oxx[k] = avz[k + 1] * txxz[k + 1] + q1[k] * dvx + q2[k] * dvz;
            ozz[k] = avz[k + 1] * tzzz[k + 1] + q1[k] * dvz + q2[k] * dvx;
            oxz[k] = avz[k + 1] * txzz[k + 1]
                   + q3[k] * ((vxn_zp[k] - vxn_z[k])
                            + (vzn_z[k + 1] - vzn_z[k]));
        }

        const int cz = b * PLANE + rz + x;
        st4(out + 0 * VOL + cz, vxn_z[0], vxn_z[1], vxn_z[2], vxn_z[3]);
        st4(out + 1 * VOL + cz, vzn_z[1], vzn_z[2], vzn_z[3], vzn_z[4]);
        st4(out + 2 * VOL + cz, oxx[0], oxx[1], oxx[2], oxx[3]);
        st4(out + 3 * VOL + cz, ozz[0], ozz[1], ozz[2], ozz[3]);
        st4(out + 4 * VOL + cz, oxz[0], oxz[1], oxz[2], oxz[3]);

        if (b < B - 1) __syncthreads();  // buffer handoff (one per shot)
    }
}

extern "C" void kernel_launch(void* const* d_in, const int* in_sizes, int n_in,
                              void* d_out, int out_size, void* d_ws, size_t ws_size,
                              hipStream_t stream) {
    const float* vp  = (const float*)d_in[0];
    const float* vs  = (const float*)d_in[1];
    const float* rho = (const float*)d_in[2];
    const float* vx  = (const float*)d_in[3];
    const float* vz  = (const float*)d_in[4];
    const float* txx = (const float*)d_in[5];
    const float* tzz = (const float*)d_in[6];
    const float* txz = (const float*)d_in[7];
    const float* dd  = (const float*)d_in[8];
    float* out = (float*)d_out;

    const int threads = 256;
    const int blocks  = NBLK;  // 4096, exact
    hipLaunchKernelGGL(wave_fused_v14, dim3(blocks), dim3(threads), 0, stream,
                       vp, vs, rho, vx, vz, txx, tzz, txz, dd, out);
}

// Round 15
// 587.148 us; speedup vs baseline: 1.0177x; 1.0177x over previous
//
#include <hip/hip_runtime.h>

// WaveCell v15 == v13 (the session's best; v14's double-buffer regressed).
// 8z x 128x LDS tile, conflict-free, hoisted staging, cross-shot prefetch.
// B=4, NZ=NX=2048, fp32, periodic wrap (pow2 dims).
//
// Session ladder (harness us): 689.7 start -> 620 (v2 width-4+B-amortize)
// -> 614 (v4 +XCD swizzle, FETCH 470->199MB) -> 609 (v9 cached stores)
// -> 597 (v12 LDS tile) -> 591 (v13 +prefetch). Dispatch ~273 -> ~181us.
// Falsified: HBM volume, request count, NT-store path, store-drain order,
// wave count (v11: 2x occupancy, no gain), double-buffer (v14: -3 blk/CU
// cancels barrier gain). Confirmed lever: CU-side bytes (LDS z-halo share).
// Residual vs ~135-145us composite floor: barrier structure + mixed-stream
// latency; remaining parameter plays model at <=10us vs +-5us noise.

constexpr int NZ = 2048;
constexpr int NX = 2048;
constexpr int B  = 4;
constexpr int PLANE = NZ * NX;      // 4,194,304
constexpr int VOL   = B * PLANE;    // 16,777,216
constexpr float DT    = 1e-3f;
constexpr float INV_H = 0.1f;       // 1/10m

constexpr int ZB   = 8;             // z-rows per block
constexpr int XR   = 128;           // x-points per block
constexpr int NROW = ZB + 2;        // staged rows z0-1 .. z0+8
constexpr int RF4  = 34;            // float4 per staged row (x0-4 .. x0+131)
constexpr int ROWF = 140;           // LDS row stride (floats), 136 + 4 pad
constexpr int F4PF = NROW * RF4;    // 340 float4 per field
constexpr int TOT  = 5 * F4PF;      // 1700 float4 staged per shot
constexpr int NBLK = PLANE / (ZB * XR);    // 4096
constexpr int NXCD = 8;
constexpr int BLK_PER_XCD = NBLK / NXCD;   // 512

typedef float f32x4 __attribute__((ext_vector_type(4)));

__device__ __forceinline__ float rcpf(float x) { return __builtin_amdgcn_rcpf(x); }
__device__ __forceinline__ float4 ld4(const float* __restrict__ p) {
    return *reinterpret_cast<const float4*>(p);
}
__device__ __forceinline__ void st4(float* __restrict__ p,
                                    float a, float b, float c, float d) {
    f32x4 v = {a, b, c, d};
    *reinterpret_cast<f32x4*>(p) = v;   // plain cached store (v9-proven)
}

__global__ __launch_bounds__(256) void wave_fused_v15(
    const float* __restrict__ vp,  const float* __restrict__ vs,
    const float* __restrict__ rho,
    const float* __restrict__ vx,  const float* __restrict__ vz,
    const float* __restrict__ txx, const float* __restrict__ tzz,
    const float* __restrict__ txz,
    const float* __restrict__ dd,
    float* __restrict__ out)
{
    __shared__ float lds[5 * NROW * ROWF];   // 28,000 B

    // XCD-band swizzle: XCD k owns 512 consecutive sb = 32 z-tiles = 256
    // contiguous z-rows -> halo rows L2-local.
    const int bid = blockIdx.x;
    const int sb  = (bid & (NXCD - 1)) * BLK_PER_XCD + (bid >> 3);
    const int tz  = sb >> 4;                 // 256 z-tiles
    const int tx  = sb & 15;                 // 16 x-tiles
    const int z0  = tz << 3;
    const int x0  = tx << 7;
    const int tid = threadIdx.x;
    const int xt  = tid & 31;                // 32 x-threads (4 pts each)
    const int zt  = tid >> 5;                // 8 z-threads

    const int z   = z0 + zt;
    const int x   = x0 + (xt << 2);
    const int zp  = (z + 1) & (NZ - 1);
    const int zm  = (z - 1) & (NZ - 1);
    const int xm1 = (x - 1) & (NX - 1);
    const int xp4 = (x + 4) & (NX - 1);
    const int rz  = z  * NX;
    const int rzp = zp * NX;
    const int rzm = zm * NX;

    // ---------- hoisted staging addresses (b-invariant) ----------
    const float* sp[7];
    int dst7[7];
    {
        #pragma unroll
        for (int k = 0; k < 7; ++k) {
            const int idx = k * 256 + tid;
            const int f   = idx / F4PF;              // 0..4 (5 when inactive)
            const int rem = idx - f * F4PF;
            const int rr  = rem / RF4;
            const int c   = rem - rr * RF4;
            const int gz  = (z0 - 1 + rr) & (NZ - 1);
            const int gx  = (x0 - 4 + (c << 2)) & (NX - 1);
            const float* fp = (f == 0) ? txx : (f == 1) ? txz
                            : (f == 2) ? tzz : (f == 3) ? vx
                            : (f == 4) ? vz  : txx;   // f==5: inactive lanes
            sp[k]   = fp + gz * NX + gx;
            dst7[k] = (f * NROW + rr) * ROWF + (c << 2);
        }
    }
    const bool act6 = tid < (TOT - 6 * 256);         // tid < 164

    // ---------- per-thread coefficients (regs, amortized over shots) -------
    float dz6[6], rz6[6];
    {
        const float4 d4 = ld4(dd + rz + x);
        dz6[0] = dd[rz + xm1]; dz6[1] = d4.x; dz6[2] = d4.y;
        dz6[3] = d4.z;         dz6[4] = d4.w; dz6[5] = dd[rz + xp4];
        const float4 r4 = ld4(rho + rz + x);
        rz6[0] = rho[rz + xm1]; rz6[1] = r4.x; rz6[2] = r4.y;
        rz6[3] = r4.z;          rz6[4] = r4.w; rz6[5] = rho[rz + xp4];
    }
    float avz[6], bvz[6], inv_c[4];
    #pragma unroll
    for (int j = 0; j < 6; ++j) {
        const float c   = 0.5f * DT * dz6[j];
        const float inv = rcpf(1.0f + c);
        avz[j] = (1.0f - c) * inv;
        bvz[j] = DT * INV_H * inv * rcpf(rz6[j]);
        if (j >= 1 && j <= 4) inv_c[j - 1] = inv;
    }
    float avzp[4], bvzp[4], avzm[4], bvzm[4];
    {
        const float4 dp = ld4(dd + rzp + x), dm = ld4(dd + rzm + x);
        const float4 rp = ld4(rho + rzp + x), rm = ld4(rho + rzm + x);
        const float dpa[4] = {dp.x, dp.y, dp.z, dp.w};
        const float dma[4] = {dm.x, dm.y, dm.z, dm.w};
        const float rpa[4] = {rp.x, rp.y, rp.z, rp.w};
        const float rma[4] = {rm.x, rm.y, rm.z, rm.w};
        #pragma unroll
        for (int k = 0; k < 4; ++k) {
            float c = 0.5f * DT * dpa[k];
            float inv = rcpf(1.0f + c);
            avzp[k] = (1.0f - c) * inv;
            bvzp[k] = DT * INV_H * inv * rcpf(rpa[k]);
            c = 0.5f * DT * dma[k];
            inv = rcpf(1.0f + c);
            avzm[k] = (1.0f - c) * inv;
            bvzm[k] = DT * INV_H * inv * rcpf(rma[k]);
        }
    }
    float q1[4], q2[4], q3[4];
    {
        const float4 vp4 = ld4(vp + rz + x), vs4 = ld4(vs + rz + x);
        const float vpa[4] = {vp4.x, vp4.y, vp4.z, vp4.w};
        const float vsa[4] = {vs4.x, vs4.y, vs4.z, vs4.w};
        #pragma unroll
        for (int k = 0; k < 4; ++k) {
            const float r   = rz6[k + 1];
            const float muv = r * vsa[k] * vsa[k];
            const float lam = r * vpa[k] * vpa[k] - 2.0f * muv;
            const float bsH = DT * INV_H * inv_c[k];
            q1[k] = bsH * (lam + 2.0f * muv);
            q2[k] = bsH * lam;
            q3[k] = bsH * muv;
        }
    }

    // LDS compute bases: staged row 0 of each field = global z0-1.
    const int lx   = 4 + (xt << 2);
    const int rowT = (0 * NROW + zt) * ROWF + lx;   // +ROWF = row z
    const int rowX = (1 * NROW + zt) * ROWF + lx;
    const int rowZ = (2 * NROW + zt) * ROWF + lx;
    const int rowV = (3 * NROW + zt) * ROWF + lx;
    const int rowW = (4 * NROW + zt) * ROWF + lx;
    auto L4 = [&](int off) -> f32x4 {
        return *reinterpret_cast<const f32x4*>(&lds[off]);
    };

    // ---------- pipelined: prefetch(b+1) hides under compute(b) ----------
    f32x4 sv[7];
    #pragma unroll
    for (int k = 0; k < 7; ++k)              // prologue: shot 0 loads
        sv[k] = *reinterpret_cast<const f32x4*>(sp[k]);

    #pragma unroll 1
    for (int b = 0; b < B; ++b) {
        if (b) __syncthreads();          // prev compute done before overwrite

        #pragma unroll
        for (int k = 0; k < 6; ++k)
            *reinterpret_cast<f32x4*>(&lds[dst7[k]]) = sv[k];
        if (act6)
            *reinterpret_cast<f32x4*>(&lds[dst7[6]]) = sv[6];
        __syncthreads();

        if (b < B - 1) {                 // prefetch next shot into dead regs
            const int nb3 = (b + 1) * PLANE;
            #pragma unroll
            for (int k = 0; k < 7; ++k)
                sv[k] = *reinterpret_cast<const f32x4*>(sp[k] + nb3);
        }

        // ---- gather row segments from LDS (all aligned ds_read_b128) ----
        float txxz[6], txzz[6], tzzz[5], tzzzp[5], txxzp[5];
        float txzzm[5], vxz[5], vzz[5];
        float txzzp4[4], tzzzm4[4], vxzp4[4], vzzm4[4];
        {
            f32x4 m, e;
            m = L4(rowT + ROWF);      e = L4(rowT + ROWF - 4);
            txxz[1] = m.x; txxz[2] = m.y; txxz[3] = m.z; txxz[4] = m.w;
            txxz[0] = e.w;            e = L4(rowT + ROWF + 4);
            txxz[5] = e.x;
            m = L4(rowX + ROWF);      e = L4(rowX + ROWF - 4);
            txzz[1] = m.x; txzz[2] = m.y; txzz[3] = m.z; txzz[4] = m.w;
            txzz[0] = e.w;            e = L4(rowX + ROWF + 4);
            txzz[5] = e.x;
            m = L4(rowZ + ROWF);      e = L4(rowZ + ROWF - 4);
            tzzz[1] = m.x; tzzz[2] = m.y; tzzz[3] = m.z; tzzz[4] = m.w;
            tzzz[0] = e.w;
            m = L4(rowZ + 2 * ROWF);  e = L4(rowZ + 2 * ROWF - 4);
            tzzzp[1] = m.x; tzzzp[2] = m.y; tzzzp[3] = m.z; tzzzp[4] = m.w;
            tzzzp[0] = e.w;
            m = L4(rowT + 2 * ROWF);  e = L4(rowT + 2 * ROWF - 4);
            txxzp[1] = m.x; txxzp[2] = m.y; txxzp[3] = m.z; txxzp[4] = m.w;
            txxzp[0] = e.w;
            m = L4(rowX);             e = L4(rowX + 4);
            txzzm[0] = m.x; txzzm[1] = m.y; txzzm[2] = m.z; txzzm[3] = m.w;
            txzzm[4] = e.x;
            m = L4(rowV + ROWF);      e = L4(rowV + ROWF + 4);
            vxz[0] = m.x; vxz[1] = m.y; vxz[2] = m.z; vxz[3] = m.w;
            vxz[4] = e.x;
            m = L4(rowW + ROWF);      e = L4(rowW + ROWF - 4);
            vzz[1] = m.x; vzz[2] = m.y; vzz[3] = m.z; vzz[4] = m.w;
            vzz[0] = e.w;
            m = L4(rowX + 2 * ROWF);
            txzzp4[0] = m.x; txzzp4[1] = m.y; txzzp4[2] = m.z; txzzp4[3] = m.w;
            m = L4(rowZ);
            tzzzm4[0] = m.x; tzzzm4[1] = m.y; tzzzm4[2] = m.z; tzzzm4[3] = m.w;
            m = L4(rowV + 2 * ROWF);
            vxzp4[0] = m.x; vxzp4[1] = m.y; vxzp4[2] = m.z; vxzp4[3] = m.w;
            m = L4(rowW);
            vzzm4[0] = m.x; vzzm4[1] = m.y; vzzm4[2] = m.z; vzzm4[3] = m.w;
        }

        // --- new velocities (leapfrog: from old stresses) ---
        float vxn_z[5];
        #pragma unroll
        for (int k = 0; k < 5; ++k)
            vxn_z[k] = avz[k + 1] * vxz[k]
                     + bvz[k + 1] * ((txxz[k + 1] - txxz[k])
                                   + (txzz[k + 1] - txzzm[k]));
        float vzn_z[5];
        #pragma unroll
        for (int k = 0; k < 5; ++k)
            vzn_z[k] = avz[k] * vzz[k]
                     + bvz[k] * ((txzz[k + 1] - txzz[k])
                               + (tzzzp[k] - tzzz[k]));
        float vxn_zp[4];
        #pragma unroll
        for (int k = 0; k < 4; ++k)
            vxn_zp[k] = avzp[k] * vxzp4[k]
                      + bvzp[k] * ((txxzp[k + 1] - txxzp[k])
                                 + (txzzp4[k] - txzz[k + 1]));
        float vzn_zm[4];
        #pragma unroll
        for (int k = 0; k < 4; ++k)
            vzn_zm[k] = avzm[k] * vzzm4[k]
                      + bvzm[k] * ((txzzm[k + 1] - txzzm[k])
                                 + (tzzz[k + 1] - tzzzm4[k]));

        // --- stress update (from new velocities) ---
        float oxx[4], ozz[4], oxz[4];
        #pragma unroll
        for (int k = 0; k < 4; ++k) {
            const float dvx = vxn_z[k + 1] - vxn_z[k];
            const float dvz = vzn_z[k + 1] - vzn_zm[k];
            oxx[k] = avz[k + 1] * txxz[k + 1] + q1[k] * dvx + q2[k] * dvz;
            ozz[k] = avz[k + 1] * tzzz[k + 1] + q1[k] * dvz + q2[k] * dvx;
            oxz[k] = avz[k + 1] * txzz[k + 1]
                   + q3[k] * ((vxn_zp[k] - vxn_z[k])
                            + (vzn_z[k + 1] - vzn_z[k]));
        }

        const int cz = b * PLANE + rz + x;
        st4(out + 0 * VOL + cz, vxn_z[0], vxn_z[1], vxn_z[2], vxn_z[3]);
        st4(out + 1 * VOL + cz, vzn_z[1], vzn_z[2], vzn_z[3], vzn_z[4]);
        st4(out + 2 * VOL + cz, oxx[0], oxx[1], oxx[2], oxx[3]);
        st4(out + 3 * VOL + cz, ozz[0], ozz[1], ozz[2], ozz[3]);
        st4(out + 4 * VOL + cz, oxz[0], oxz[1], oxz[2], oxz[3]);
    }
}

extern "C" void kernel_launch(void* const* d_in, const int* in_sizes, int n_in,
                              void* d_out, int out_size, void* d_ws, size_t ws_size,
                              hipStream_t stream) {
    const float* vp  = (const float*)d_in[0];
    const float* vs  = (const float*)d_in[1];
    const float* rho = (const float*)d_in[2];
    const float* vx  = (const float*)d_in[3];
    const float* vz  = (const float*)d_in[4];
    const float* txx = (const float*)d_in[5];
    const float* tzz = (const float*)d_in[6];
    const float* txz = (const float*)d_in[7];
    const float* dd  = (const float*)d_in[8];
    float* out = (float*)d_out;

    const int threads = 256;
    const int blocks  = NBLK;  // 4096, exact
    hipLaunchKernelGGL(wave_fused_v15, dim3(blocks), dim3(threads), 0, stream,
                       vp, vs, rho, vx, vz, txx, tzz, txz, dd, out);
}